// Round 1
// baseline (1249.257 us; speedup 1.0000x reference)
//
#include <hip/hip_runtime.h>
#include <hip/hip_bf16.h>
#include <math.h>

typedef float f32x4 __attribute__((ext_vector_type(4)));
typedef float f32x2 __attribute__((ext_vector_type(2)));

#define B_ 32
#define C_ 64
#define L_ 512
#define P_ 16
#define S_ 4
#define NP_ 125
#define D_ 128
#define INNER_ 256
#define NL_ 4
#define F_ 96
#define CF_ (C_*F_)      /* 6144  */
#define M_ (B_*NP_)      /* 4000  */
#define CP_ (C_*P_)      /* 1024  */
#define KF_ (NP_*D_)     /* 16000 */
#define EPS_ 1e-5f

// ---------------------------------------------------------------------------
// Kernel 1: patch embedding GEMM  h[m,d] = sum_q xp[m,q]*peW[d,q] + peb + PE
//   M=4000 rows, K=1024, N=128.  BM=32, BN=64, BK=32; 2x4 micro-tile.
// ---------------------------------------------------------------------------
__global__ __launch_bounds__(256) void patch_embed_k(
    const float* __restrict__ x, const float* __restrict__ peW,
    const float* __restrict__ peb, float* __restrict__ h)
{
  __shared__ float Xs[32][33];   // [kk][row]
  __shared__ float Ws[32][68];   // [kk][col], stride 68 keeps 16B alignment
  int tid = threadIdx.x;
  int m0 = blockIdx.x * 32;
  int cb = blockIdx.y * 64;
  int tr = tid >> 4, tc = tid & 15;    // rows tr*2.., cols tc*4..
  int lk = tid & 31, lr = tid >> 5;    // staging: k-lane, row/col pass lane

  int xbase[4];
#pragma unroll
  for (int rp = 0; rp < 4; ++rp) {
    int m = m0 + lr + rp*8;
    int b = m / 125, kp = m - b*125;
    xbase[rp] = b*(C_*L_) + kp*S_;
  }

  float acc[2][4] = {};
  for (int k0 = 0; k0 < CP_; k0 += 32) {
    int kq = k0 + lk;
    int c = kq >> 4, p = kq & 15;
    int xoff = c*L_ + p;
#pragma unroll
    for (int rp = 0; rp < 4; ++rp)
      Xs[lk][lr + rp*8] = x[xbase[rp] + xoff];
#pragma unroll
    for (int cp = 0; cp < 8; ++cp) {
      int cc = lr + cp*8;
      Ws[lk][cc] = peW[(cb + cc)*CP_ + kq];
    }
    __syncthreads();
#pragma unroll
    for (int kk = 0; kk < 32; ++kk) {
      float x0 = Xs[kk][tr*2], x1 = Xs[kk][tr*2 + 1];
      f32x4 w = *(const f32x4*)&Ws[kk][tc*4];
#pragma unroll
      for (int j = 0; j < 4; ++j) { acc[0][j] += x0*w[j]; acc[1][j] += x1*w[j]; }
    }
    __syncthreads();
  }
  // epilogue: + bias + sincos positional encoding
#pragma unroll
  for (int i = 0; i < 2; ++i) {
    int m = m0 + tr*2 + i;
    int kp = m % 125;
#pragma unroll
    for (int j = 0; j < 4; ++j) {
      int d = cb + tc*4 + j;
      float freq = expf(-9.2103403719761836f * (float)(d >> 1) * (1.0f/64.0f));
      float ang = (float)kp * freq;
      float pe = (d & 1) ? cosf(ang) : sinf(ang);
      h[m*D_ + d] = acc[i][j] + peb[d] + pe;
    }
  }
}

// ---------------------------------------------------------------------------
// Kernel 2: fused RMSNorm + a/b projections.
//   grid (125, 4): g<2 -> a cols g*128, g>=2 -> b cols (g-2)*128.
//   M=4000, K=128, 128 cols per block; 2x8 micro-tile.
// ---------------------------------------------------------------------------
__global__ __launch_bounds__(256) void ab_proj_k(
    const float* __restrict__ h, const float* __restrict__ nw,
    const float* __restrict__ aW, const float* __restrict__ bW,
    float* __restrict__ aout, float* __restrict__ bout)
{
  __shared__ float Hs[32][33];
  __shared__ float Ws[32][132];
  __shared__ float rs[32];
  int tid = threadIdx.x;
  int m0 = blockIdx.x * 32;
  int g = blockIdx.y;
  const float* W = (g < 2) ? aW : bW;
  float* out = (g < 2) ? aout : bout;
  int cb = (g & 1) * 128;

  { // per-row rmsnorm scale (rows fully owned by this block)
    int row = tid >> 3, seg = tid & 7;
    const f32x4* hp = (const f32x4*)(h + (m0 + row)*D_ + seg*16);
    float ss = 0.f;
#pragma unroll
    for (int q = 0; q < 4; ++q) {
      f32x4 v = hp[q];
      ss += v[0]*v[0] + v[1]*v[1] + v[2]*v[2] + v[3]*v[3];
    }
    ss += __shfl_xor(ss, 1); ss += __shfl_xor(ss, 2); ss += __shfl_xor(ss, 4);
    if (seg == 0) rs[row] = rsqrtf(ss*(1.0f/D_) + EPS_);
  }
  __syncthreads();

  int tr = tid >> 4, tc = tid & 15;
  int lk = tid & 31, lr = tid >> 5;
  float acc[2][8] = {};
  for (int k0 = 0; k0 < D_; k0 += 32) {
    float nwv = nw[k0 + lk];
#pragma unroll
    for (int rp = 0; rp < 4; ++rp) {
      int r = lr + rp*8;
      Hs[lk][r] = h[(m0 + r)*D_ + k0 + lk] * rs[r] * nwv;
    }
#pragma unroll
    for (int cp = 0; cp < 16; ++cp) {
      int cc = lr + cp*8;
      Ws[lk][cc] = W[(cb + cc)*D_ + k0 + lk];
    }
    __syncthreads();
#pragma unroll
    for (int kk = 0; kk < 32; ++kk) {
      float x0 = Hs[kk][tr*2], x1 = Hs[kk][tr*2 + 1];
      f32x4 wa = *(const f32x4*)&Ws[kk][tc*8];
      f32x4 wb = *(const f32x4*)&Ws[kk][tc*8 + 4];
#pragma unroll
      for (int j = 0; j < 4; ++j) {
        acc[0][j]   += x0*wa[j]; acc[0][4+j] += x0*wb[j];
        acc[1][j]   += x1*wa[j]; acc[1][4+j] += x1*wb[j];
      }
    }
    __syncthreads();
  }
#pragma unroll
  for (int i = 0; i < 2; ++i) {
    int m = m0 + tr*2 + i;
#pragma unroll
    for (int j = 0; j < 8; ++j)
      out[m*INNER_ + cb + tc*8 + j] = acc[i][j];
  }
}

// ---------------------------------------------------------------------------
// Kernel 3: depthwise conv(K=5,pad=2) + SiLU + selective scan + (*b) -> sb
//   grid (B, 2): one block per (batch, 128-channel half). Sequential over NP.
// ---------------------------------------------------------------------------
__global__ __launch_bounds__(128) void conv_scan_k(
    const float* __restrict__ a, const float* __restrict__ bm,
    const float* __restrict__ cw, const float* __restrict__ cbias,
    const float* __restrict__ alpha, const float* __restrict__ beta,
    const float* __restrict__ gamma, const float* __restrict__ delta,
    float* __restrict__ sbuf)
{
  __shared__ float als[NP_*128];   // 64000 B
  int tid = threadIdx.x;
  int b = blockIdx.x;
  int half = blockIdx.y;
  const float* abase = a + b*(NP_*INNER_) + half*128;
  for (int t = tid; t < NP_*32; t += 128) {   // 4000 f32x4
    int k = t >> 5; int q = (t & 31)*4;
    *(f32x4*)&als[k*128 + q] = *(const f32x4*)&abase[k*INNER_ + q];
  }
  __syncthreads();

  int i = half*128 + tid;
  float w0 = cw[i*5+0], w1 = cw[i*5+1], w2 = cw[i*5+2], w3 = cw[i*5+3], w4 = cw[i*5+4];
  float bias = cbias[i];
  float sa = 1.f/(1.f + expf(-alpha[i]));
  float bt = beta[i], gm = gamma[i], dl = delta[i];

  float q0 = 0.f, q1 = 0.f, q2 = als[tid], q3 = als[128 + tid], q4 = als[256 + tid];
  float s = 0.f;
  const float* bp = bm + b*(NP_*INNER_) + i;
  float* sp = sbuf + b*(NP_*INNER_) + i;
  for (int k = 0; k < NP_; ++k) {
    float v = w0*q0 + w1*q1 + w2*q2 + w3*q3 + w4*q4 + bias;
    float u = v / (1.f + expf(-v));            // silu
    s = sa*s + bt*u;
    float y = gm*s + dl*u;
    sp[0] = y * bp[0];
    sp += INNER_; bp += INNER_;
    q0 = q1; q1 = q2; q2 = q3; q3 = q4;
    q4 = (k + 3 < NP_) ? als[(k + 3)*128 + tid] : 0.f;
  }
}

// ---------------------------------------------------------------------------
// Kernel 4: out projection + residual.  h[m,d] += sum_i sb[m,i]*oW[d,i]
//   M=4000, K=256, N=128.  BM=32; 2x8 micro-tile.
// ---------------------------------------------------------------------------
__global__ __launch_bounds__(256) void out_proj_k(
    const float* __restrict__ sbuf, const float* __restrict__ oW,
    float* __restrict__ h)
{
  __shared__ float Ss[32][33];
  __shared__ float Ws[32][132];
  int tid = threadIdx.x;
  int m0 = blockIdx.x * 32;
  int tr = tid >> 4, tc = tid & 15;
  int lk = tid & 31, lr = tid >> 5;
  float acc[2][8] = {};
  for (int k0 = 0; k0 < INNER_; k0 += 32) {
#pragma unroll
    for (int rp = 0; rp < 4; ++rp) {
      int r = lr + rp*8;
      Ss[lk][r] = sbuf[(m0 + r)*INNER_ + k0 + lk];
    }
#pragma unroll
    for (int cp = 0; cp < 16; ++cp) {
      int cc = lr + cp*8;
      Ws[lk][cc] = oW[cc*INNER_ + k0 + lk];
    }
    __syncthreads();
#pragma unroll
    for (int kk = 0; kk < 32; ++kk) {
      float x0 = Ss[kk][tr*2], x1 = Ss[kk][tr*2 + 1];
      f32x4 wa = *(const f32x4*)&Ws[kk][tc*8];
      f32x4 wb = *(const f32x4*)&Ws[kk][tc*8 + 4];
#pragma unroll
      for (int j = 0; j < 4; ++j) {
        acc[0][j]   += x0*wa[j]; acc[0][4+j] += x0*wb[j];
        acc[1][j]   += x1*wa[j]; acc[1][4+j] += x1*wb[j];
      }
    }
    __syncthreads();
  }
#pragma unroll
  for (int i = 0; i < 2; ++i) {
    int m = m0 + tr*2 + i;
#pragma unroll
    for (int j = 0; j < 8; ++j)
      h[m*D_ + tc*8 + j] += acc[i][j];
  }
}

// ---------------------------------------------------------------------------
// Kernel 5: final RMSNorm  hn = rmsnorm(h, normf_w).  One wave per row.
// ---------------------------------------------------------------------------
__global__ __launch_bounds__(256) void rmsnorm_final_k(
    const float* __restrict__ h, const float* __restrict__ w,
    float* __restrict__ hn)
{
  int row = blockIdx.x*4 + (threadIdx.x >> 6);
  int lane = threadIdx.x & 63;
  f32x2 v = ((const f32x2*)(h + row*D_))[lane];
  float ss = v[0]*v[0] + v[1]*v[1];
#pragma unroll
  for (int m = 1; m < 64; m <<= 1) ss += __shfl_xor(ss, m);
  float rsc = rsqrtf(ss*(1.0f/D_) + EPS_);
  f32x2 wv = ((const f32x2*)w)[lane];
  f32x2 o; o[0] = v[0]*rsc*wv[0]; o[1] = v[1]*rsc*wv[1];
  ((f32x2*)(hn + row*D_))[lane] = o;
}

// ---------------------------------------------------------------------------
// Kernel 6: final GEMM  out[b, n] = sum_q flat[b,q]*out_W[n,q] + out_b[n]
//   M=32, N=6144, K=16000.  Block: 32 cols (4 waves x 8 cols), Kt=320.
//   Lane = (row-group rg 0..7) x (k-slice ks 0..7); 4x8 register tile;
//   out_W streamed once (nontemporal), flat staged in LDS.
// ---------------------------------------------------------------------------
__global__ __launch_bounds__(256) void final_gemm_k(
    const float* __restrict__ flat, const float* __restrict__ W,
    const float* __restrict__ ob, float* __restrict__ out)
{
  __shared__ float Fs[32][324];   // 32 rows x 320 (+4 pad) = 41472 B
  int tid = threadIdx.x;
  int wave = tid >> 6, lane = tid & 63;
  int rg = lane >> 3, ks = lane & 7;
  int mycol = blockIdx.x*32 + wave*8;
  float acc[4][8] = {};

  for (int k0 = 0; k0 < KF_; k0 += 320) {
    for (int t = tid; t < 32*80; t += 256) {
      int r = t / 80; int kq = (t - r*80)*4;
      *(f32x4*)&Fs[r][kq] = *(const f32x4*)&flat[r*KF_ + k0 + kq];
    }
    __syncthreads();
#pragma unroll
    for (int j = 0; j < 10; ++j) {
      int kb = ks*4 + j*32;
      f32x4 wv[8];
#pragma unroll
      for (int c = 0; c < 8; ++c)
        wv[c] = __builtin_nontemporal_load((const f32x4*)&W[(mycol + c)*KF_ + k0 + kb]);
      f32x4 fv[4];
#pragma unroll
      for (int r = 0; r < 4; ++r)
        fv[r] = *(const f32x4*)&Fs[rg*4 + r][kb];
#pragma unroll
      for (int r = 0; r < 4; ++r)
#pragma unroll
        for (int c = 0; c < 8; ++c)
#pragma unroll
          for (int q = 0; q < 4; ++q)
            acc[r][c] += fv[r][q]*wv[c][q];
    }
    __syncthreads();
  }
  // reduce over the 8 k-slices (lanes ks=0..7 within each rg group)
#pragma unroll
  for (int r = 0; r < 4; ++r)
#pragma unroll
    for (int c = 0; c < 8; ++c) {
      float v = acc[r][c];
      v += __shfl_xor(v, 1); v += __shfl_xor(v, 2); v += __shfl_xor(v, 4);
      acc[r][c] = v;
    }
  if (ks == 0) {
#pragma unroll
    for (int r = 0; r < 4; ++r)
#pragma unroll
      for (int c = 0; c < 8; ++c)
        out[(rg*4 + r)*CF_ + mycol + c] = acc[r][c] + ob[mycol + c];
  }
}

// ---------------------------------------------------------------------------
extern "C" void kernel_launch(void* const* d_in, const int* in_sizes, int n_in,
                              void* d_out, int out_size, void* d_ws, size_t ws_size,
                              hipStream_t stream) {
  const float* x      = (const float*)d_in[0];
  const float* peW    = (const float*)d_in[1];
  const float* peb    = (const float*)d_in[2];
  const float* norm_w = (const float*)d_in[3];
  const float* ipaW   = (const float*)d_in[4];
  const float* ipbW   = (const float*)d_in[5];
  const float* convW  = (const float*)d_in[6];
  const float* convb  = (const float*)d_in[7];
  const float* alpha  = (const float*)d_in[8];
  const float* beta   = (const float*)d_in[9];
  const float* gamma  = (const float*)d_in[10];
  const float* delta  = (const float*)d_in[11];
  const float* opW    = (const float*)d_in[12];
  const float* normf  = (const float*)d_in[13];
  const float* outW   = (const float*)d_in[14];
  const float* outb   = (const float*)d_in[15];
  float* out = (float*)d_out;

  // workspace layout (floats): needs 16.4 MB
  float* ws   = (float*)d_ws;
  float* h    = ws;                 // 512000
  float* hn   = ws + 512000;        // 512000
  float* abuf = ws + 1024000;       // 1024000
  float* bbuf = ws + 2048000;       // 1024000
  float* sbuf = ws + 3072000;       // 1024000

  patch_embed_k<<<dim3(125, 2), 256, 0, stream>>>(x, peW, peb, h);
  for (int l = 0; l < NL_; ++l) {
    ab_proj_k<<<dim3(125, 4), 256, 0, stream>>>(
        h, norm_w + l*D_, ipaW + l*INNER_*D_, ipbW + l*INNER_*D_, abuf, bbuf);
    conv_scan_k<<<dim3(B_, 2), 128, 0, stream>>>(
        abuf, bbuf, convW + l*INNER_*5, convb + l*INNER_,
        alpha + l*INNER_, beta + l*INNER_, gamma + l*INNER_, delta + l*INNER_, sbuf);
    out_proj_k<<<dim3(125), 256, 0, stream>>>(sbuf, opW + l*D_*INNER_, h);
  }
  rmsnorm_final_k<<<dim3(1000), 256, 0, stream>>>(h, normf, hn);
  final_gemm_k<<<dim3(192), 256, 0, stream>>>(hn, outW, outb, out);
}

// Round 3
// 1103.381 us; speedup vs baseline: 1.1322x; 1.1322x over previous
//
#include <hip/hip_runtime.h>
#include <hip/hip_bf16.h>
#include <math.h>

typedef float f32x4 __attribute__((ext_vector_type(4)));
typedef float f32x2 __attribute__((ext_vector_type(2)));

#define B_ 32
#define C_ 64
#define L_ 512
#define P_ 16
#define S_ 4
#define NP_ 125
#define D_ 128
#define INNER_ 256
#define NL_ 4
#define F_ 96
#define CF_ (C_*F_)      /* 6144  */
#define M_ (B_*NP_)      /* 4000  */
#define CP_ (C_*P_)      /* 1024  */
#define KF_ (NP_*D_)     /* 16000 */
#define EPS_ 1e-5f
#define KS_ 5
#define CHUNK_ 3200      /* 12 windows of 256 + 1 half window of 128 */

// ---------------------------------------------------------------------------
// Kernel 1: patch embedding GEMM  h[m,d] = sum_q xp[m,q]*peW[d,q] + peb + PE
//   M=4000 rows, K=1024, N=128.  BM=32, BN=64, BK=32; 2x4 micro-tile.
// ---------------------------------------------------------------------------
__global__ __launch_bounds__(256) void patch_embed_k(
    const float* __restrict__ x, const float* __restrict__ peW,
    const float* __restrict__ peb, float* __restrict__ h)
{
  __shared__ float Xs[32][34];   // [kk][row], stride 34 -> 8B-aligned f32x2 reads
  __shared__ float Ws[32][68];   // [kk][col], stride 68 keeps 16B alignment
  int tid = threadIdx.x;
  int m0 = blockIdx.x * 32;
  int cb = blockIdx.y * 64;
  int tr = tid >> 4, tc = tid & 15;    // rows tr*2.., cols tc*4..
  int lk = tid & 31, lr = tid >> 5;    // staging: k-lane, row/col pass lane

  int xbase[4];
#pragma unroll
  for (int rp = 0; rp < 4; ++rp) {
    int m = m0 + lr + rp*8;
    int b = m / 125, kp = m - b*125;
    xbase[rp] = b*(C_*L_) + kp*S_;
  }

  float acc[2][4] = {};
  for (int k0 = 0; k0 < CP_; k0 += 32) {
    int kq = k0 + lk;
    int c = kq >> 4, p = kq & 15;
    int xoff = c*L_ + p;
#pragma unroll
    for (int rp = 0; rp < 4; ++rp)
      Xs[lk][lr + rp*8] = x[xbase[rp] + xoff];
#pragma unroll
    for (int cp = 0; cp < 8; ++cp) {
      int cc = lr + cp*8;
      Ws[lk][cc] = peW[(cb + cc)*CP_ + kq];
    }
    __syncthreads();
#pragma unroll
    for (int kk = 0; kk < 32; ++kk) {
      f32x2 xv = *(const f32x2*)&Xs[kk][tr*2];
      f32x4 w = *(const f32x4*)&Ws[kk][tc*4];
#pragma unroll
      for (int j = 0; j < 4; ++j) { acc[0][j] += xv[0]*w[j]; acc[1][j] += xv[1]*w[j]; }
    }
    __syncthreads();
  }
  // epilogue: + bias + sincos positional encoding
#pragma unroll
  for (int i = 0; i < 2; ++i) {
    int m = m0 + tr*2 + i;
    int kp = m % 125;
#pragma unroll
    for (int j = 0; j < 4; ++j) {
      int d = cb + tc*4 + j;
      float freq = expf(-9.2103403719761836f * (float)(d >> 1) * (1.0f/64.0f));
      float ang = (float)kp * freq;
      float pe = (d & 1) ? cosf(ang) : sinf(ang);
      h[m*D_ + d] = acc[i][j] + peb[d] + pe;
    }
  }
}

// ---------------------------------------------------------------------------
// Kernel 2: fused RMSNorm + a/b projections.
//   grid (125, 4): g<2 -> a cols g*128, g>=2 -> b cols (g-2)*128.
//   M=4000, K=128, 128 cols per block; 4x4 micro-tile (b128+b128 per k-step).
// ---------------------------------------------------------------------------
__global__ __launch_bounds__(256) void ab_proj_k(
    const float* __restrict__ h, const float* __restrict__ nw,
    const float* __restrict__ aW, const float* __restrict__ bW,
    float* __restrict__ aout, float* __restrict__ bout)
{
  __shared__ float Hs[32][36];   // [kk][row], stride 36 -> 16B aligned
  __shared__ float Ws[32][132];
  __shared__ float rs[32];
  int tid = threadIdx.x;
  int m0 = blockIdx.x * 32;
  int g = blockIdx.y;
  const float* W = (g < 2) ? aW : bW;
  float* out = (g < 2) ? aout : bout;
  int cb = (g & 1) * 128;

  { // per-row rmsnorm scale (rows fully owned by this block)
    int row = tid >> 3, seg = tid & 7;
    const f32x4* hp = (const f32x4*)(h + (m0 + row)*D_ + seg*16);
    float ss = 0.f;
#pragma unroll
    for (int q = 0; q < 4; ++q) {
      f32x4 v = hp[q];
      ss += v[0]*v[0] + v[1]*v[1] + v[2]*v[2] + v[3]*v[3];
    }
    ss += __shfl_xor(ss, 1); ss += __shfl_xor(ss, 2); ss += __shfl_xor(ss, 4);
    if (seg == 0) rs[row] = rsqrtf(ss*(1.0f/D_) + EPS_);
  }
  __syncthreads();

  int tr = tid >> 5;   // 0..7  -> rows tr*4..
  int tc = tid & 31;   // 0..31 -> cols tc*4..
  int lk = tid & 31, lr = tid >> 5;
  float acc[4][4] = {};
  for (int k0 = 0; k0 < D_; k0 += 32) {
    float nwv = nw[k0 + lk];
#pragma unroll
    for (int rp = 0; rp < 4; ++rp) {
      int r = lr + rp*8;
      Hs[lk][r] = h[(m0 + r)*D_ + k0 + lk] * rs[r] * nwv;
    }
#pragma unroll
    for (int cp = 0; cp < 16; ++cp) {
      int cc = lr + cp*8;
      Ws[lk][cc] = W[(cb + cc)*D_ + k0 + lk];
    }
    __syncthreads();
#pragma unroll
    for (int kk = 0; kk < 32; ++kk) {
      f32x4 hv = *(const f32x4*)&Hs[kk][tr*4];
      f32x4 wv = *(const f32x4*)&Ws[kk][tc*4];
#pragma unroll
      for (int i = 0; i < 4; ++i)
#pragma unroll
        for (int j = 0; j < 4; ++j)
          acc[i][j] += hv[i]*wv[j];
    }
    __syncthreads();
  }
#pragma unroll
  for (int i = 0; i < 4; ++i) {
    int m = m0 + tr*4 + i;
    f32x4 v; v[0]=acc[i][0]; v[1]=acc[i][1]; v[2]=acc[i][2]; v[3]=acc[i][3];
    *(f32x4*)&out[m*INNER_ + cb + tc*4] = v;
  }
}

// ---------------------------------------------------------------------------
// Kernel 3: depthwise conv(K=5,pad=2) + SiLU + selective scan + (*b) -> sb
//   grid (B, 2): one block per (batch, 128-channel half). Serial over NP;
//   loop-carried dep is a single FMA (s = sa*s + bt*u); conv/silu pipeline.
//   (The two-phase parallel variant had a cross-wave overwrite race at the
//   ascending/descending meeting point — reverted to this proven form.)
// ---------------------------------------------------------------------------
__global__ __launch_bounds__(128) void conv_scan_k(
    const float* __restrict__ a, const float* __restrict__ bm,
    const float* __restrict__ cw, const float* __restrict__ cbias,
    const float* __restrict__ alpha, const float* __restrict__ beta,
    const float* __restrict__ gamma, const float* __restrict__ delta,
    float* __restrict__ sbuf)
{
  __shared__ float als[NP_*128];   // 64000 B
  int tid = threadIdx.x;
  int b = blockIdx.x;
  int half = blockIdx.y;
  const float* abase = a + b*(NP_*INNER_) + half*128;
  for (int t = tid; t < NP_*32; t += 128) {   // 4000 f32x4
    int k = t >> 5; int q = (t & 31)*4;
    *(f32x4*)&als[k*128 + q] = *(const f32x4*)&abase[k*INNER_ + q];
  }
  __syncthreads();

  int i = half*128 + tid;
  float w0 = cw[i*5+0], w1 = cw[i*5+1], w2 = cw[i*5+2], w3 = cw[i*5+3], w4 = cw[i*5+4];
  float bias = cbias[i];
  float sa = 1.f/(1.f + expf(-alpha[i]));
  float bt = beta[i], gm = gamma[i], dl = delta[i];

  float q0 = 0.f, q1 = 0.f, q2 = als[tid], q3 = als[128 + tid], q4 = als[256 + tid];
  float s = 0.f;
  const float* bp = bm + b*(NP_*INNER_) + i;
  float* sp = sbuf + b*(NP_*INNER_) + i;
  for (int k = 0; k < NP_; ++k) {
    float v = w0*q0 + w1*q1 + w2*q2 + w3*q3 + w4*q4 + bias;
    float u = v / (1.f + expf(-v));            // silu
    s = sa*s + bt*u;
    float y = gm*s + dl*u;
    sp[0] = y * bp[0];
    sp += INNER_; bp += INNER_;
    q0 = q1; q1 = q2; q2 = q3; q3 = q4;
    q4 = (k + 3 < NP_) ? als[(k + 3)*128 + tid] : 0.f;
  }
}

// ---------------------------------------------------------------------------
// Kernel 4: out projection + residual.  h[m,d] += sum_i sb[m,i]*oW[d,i]
//   grid (125, 2): 32 rows x 64 cols per block; 2x4 micro-tile.
// ---------------------------------------------------------------------------
__global__ __launch_bounds__(256) void out_proj_k(
    const float* __restrict__ sbuf, const float* __restrict__ oW,
    float* __restrict__ h)
{
  __shared__ float Ss[32][34];
  __shared__ float Ws[32][68];
  int tid = threadIdx.x;
  int m0 = blockIdx.x * 32;
  int cb = blockIdx.y * 64;
  int tr = tid >> 4, tc = tid & 15;
  int lk = tid & 31, lr = tid >> 5;
  float acc[2][4] = {};
  for (int k0 = 0; k0 < INNER_; k0 += 32) {
#pragma unroll
    for (int rp = 0; rp < 4; ++rp) {
      int r = lr + rp*8;
      Ss[lk][r] = sbuf[(m0 + r)*INNER_ + k0 + lk];
    }
#pragma unroll
    for (int cp = 0; cp < 8; ++cp) {
      int cc = lr + cp*8;
      Ws[lk][cc] = oW[(cb + cc)*INNER_ + k0 + lk];
    }
    __syncthreads();
#pragma unroll
    for (int kk = 0; kk < 32; ++kk) {
      f32x2 sv = *(const f32x2*)&Ss[kk][tr*2];
      f32x4 wv = *(const f32x4*)&Ws[kk][tc*4];
#pragma unroll
      for (int j = 0; j < 4; ++j) {
        acc[0][j] += sv[0]*wv[j];
        acc[1][j] += sv[1]*wv[j];
      }
    }
    __syncthreads();
  }
#pragma unroll
  for (int i = 0; i < 2; ++i) {
    int m = m0 + tr*2 + i;
#pragma unroll
    for (int j = 0; j < 4; ++j)
      h[m*D_ + cb + tc*4 + j] += acc[i][j];
  }
}

// ---------------------------------------------------------------------------
// Kernel 5: final RMSNorm  hn = rmsnorm(h, normf_w).  One wave per row.
// ---------------------------------------------------------------------------
__global__ __launch_bounds__(256) void rmsnorm_final_k(
    const float* __restrict__ h, const float* __restrict__ w,
    float* __restrict__ hn)
{
  int row = blockIdx.x*4 + (threadIdx.x >> 6);
  int lane = threadIdx.x & 63;
  f32x2 v = ((const f32x2*)(h + row*D_))[lane];
  float ss = v[0]*v[0] + v[1]*v[1];
#pragma unroll
  for (int m = 1; m < 64; m <<= 1) ss += __shfl_xor(ss, m);
  float rsc = rsqrtf(ss*(1.0f/D_) + EPS_);
  f32x2 wv = ((const f32x2*)w)[lane];
  f32x2 o; o[0] = v[0]*rsc*wv[0]; o[1] = v[1]*rsc*wv[1];
  ((f32x2*)(hn + row*D_))[lane] = o;
}

// ---------------------------------------------------------------------------
// Kernel 6: final GEMM, split-K.
//   part[ks][32][6144] = flat[32, ksChunk] @ W[6144, ksChunk]^T
//   Grid (384, 5), 512 threads (8 waves x 2 cols = 16 cols/block).
//   Lanes cover contiguous K (1 KB per W load instr); each lane accumulates
//   all 32 rows x 2 cols; butterfly k-reduce at the end.
//   flat window double-buffered in LDS (2 x 32 x 256 f32 = 64 KB).
// ---------------------------------------------------------------------------
__global__ __launch_bounds__(512, 4) void final_gemm_k(
    const float* __restrict__ flat, const float* __restrict__ W,
    float* __restrict__ part)
{
  __shared__ float Fs[2][32][256];
  int tid = threadIdx.x;
  int wave = tid >> 6, lane = tid & 63;
  int c0 = blockIdx.x * 16 + wave * 2;
  int ks = blockIdx.y;
  int kbase = ks * CHUNK_;

  int srow[4], scol[4];
#pragma unroll
  for (int i = 0; i < 4; ++i) { int q = tid + i*512; srow[i] = q >> 6; scol[i] = (q & 63)*4; }

  const float* wp0 = W + (size_t)c0 * KF_ + kbase + lane*4;
  const float* wp1 = wp0 + KF_;

  float acc[32][2];
#pragma unroll
  for (int r = 0; r < 32; ++r) { acc[r][0] = 0.f; acc[r][1] = 0.f; }

  // prologue: stage window 0, load W for window 0
#pragma unroll
  for (int i = 0; i < 4; ++i)
    *(f32x4*)&Fs[0][srow[i]][scol[i]] = *(const f32x4*)&flat[srow[i]*KF_ + kbase + scol[i]];
  f32x4 wa = *(const f32x4*)wp0;
  f32x4 wb = *(const f32x4*)wp1;
  __syncthreads();

  for (int j = 0; j < 12; ++j) {
    int cur = j & 1;
    f32x4 sr[4], wan, wbn;
    if (j < 11) {
      int koff = kbase + (j + 1)*256;
#pragma unroll
      for (int i = 0; i < 4; ++i)
        sr[i] = *(const f32x4*)&flat[srow[i]*KF_ + koff + scol[i]];
      wan = *(const f32x4*)(wp0 + (j + 1)*256);
      wbn = *(const f32x4*)(wp1 + (j + 1)*256);
    }
#pragma unroll
    for (int r = 0; r < 32; ++r) {
      f32x4 fv = *(const f32x4*)&Fs[cur][r][lane*4];
#pragma unroll
      for (int q = 0; q < 4; ++q) {
        acc[r][0] += fv[q]*wa[q];
        acc[r][1] += fv[q]*wb[q];
      }
    }
    if (j < 11) {
#pragma unroll
      for (int i = 0; i < 4; ++i)
        *(f32x4*)&Fs[cur ^ 1][srow[i]][scol[i]] = sr[i];
      wa = wan; wb = wbn;
    }
    __syncthreads();
  }

  // half window: 128 floats at kbase+3072, f32x2 per lane
  {
    int koff = kbase + 3072;
#pragma unroll
    for (int i = 0; i < 2; ++i) {
      int q = tid + i*512; int row = q >> 5; int col = (q & 31)*4;
      *(f32x4*)&Fs[0][row][col] = *(const f32x4*)&flat[row*KF_ + koff + col];
    }
    f32x2 wa2 = *(const f32x2*)(W + (size_t)c0*KF_ + koff + lane*2);
    f32x2 wb2 = *(const f32x2*)(W + (size_t)(c0 + 1)*KF_ + koff + lane*2);
    __syncthreads();
#pragma unroll
    for (int r = 0; r < 32; ++r) {
      f32x2 fv = *(const f32x2*)&Fs[0][r][lane*2];
      acc[r][0] += fv[0]*wa2[0] + fv[1]*wa2[1];
      acc[r][1] += fv[0]*wb2[0] + fv[1]*wb2[1];
    }
  }

  // butterfly k-reduce across the 64 lanes, lane 0 stores
#pragma unroll
  for (int r = 0; r < 32; ++r)
#pragma unroll
    for (int c = 0; c < 2; ++c) {
      float v = acc[r][c];
      v += __shfl_xor(v, 1);  v += __shfl_xor(v, 2);  v += __shfl_xor(v, 4);
      v += __shfl_xor(v, 8);  v += __shfl_xor(v, 16); v += __shfl_xor(v, 32);
      acc[r][c] = v;
    }
  if (lane == 0) {
    float* pp = part + (size_t)ks*(32*CF_) + c0;
#pragma unroll
    for (int r = 0; r < 32; ++r) {
      pp[r*CF_ + 0] = acc[r][0];
      pp[r*CF_ + 1] = acc[r][1];
    }
  }
}

// ---------------------------------------------------------------------------
// Kernel 7: reduce the KS_ partials + bias -> out[32][6144]
// ---------------------------------------------------------------------------
__global__ __launch_bounds__(256) void final_reduce_k(
    const float* __restrict__ part, const float* __restrict__ ob,
    float* __restrict__ out)
{
  int idx = (blockIdx.x*256 + threadIdx.x)*4;     // < 196608
  f32x4 s = *(const f32x4*)&part[idx];
#pragma unroll
  for (int ks = 1; ks < KS_; ++ks) {
    f32x4 p = *(const f32x4*)&part[ks*(32*CF_) + idx];
    s[0] += p[0]; s[1] += p[1]; s[2] += p[2]; s[3] += p[3];
  }
  int n = idx % CF_;
  f32x4 bv = *(const f32x4*)&ob[n];
  s[0] += bv[0]; s[1] += bv[1]; s[2] += bv[2]; s[3] += bv[3];
  *(f32x4*)&out[idx] = s;
}

// ---------------------------------------------------------------------------
extern "C" void kernel_launch(void* const* d_in, const int* in_sizes, int n_in,
                              void* d_out, int out_size, void* d_ws, size_t ws_size,
                              hipStream_t stream) {
  const float* x      = (const float*)d_in[0];
  const float* peW    = (const float*)d_in[1];
  const float* peb    = (const float*)d_in[2];
  const float* norm_w = (const float*)d_in[3];
  const float* ipaW   = (const float*)d_in[4];
  const float* ipbW   = (const float*)d_in[5];
  const float* convW  = (const float*)d_in[6];
  const float* convb  = (const float*)d_in[7];
  const float* alpha  = (const float*)d_in[8];
  const float* beta   = (const float*)d_in[9];
  const float* gamma  = (const float*)d_in[10];
  const float* delta  = (const float*)d_in[11];
  const float* opW    = (const float*)d_in[12];
  const float* normf  = (const float*)d_in[13];
  const float* outW   = (const float*)d_in[14];
  const float* outb   = (const float*)d_in[15];
  float* out = (float*)d_out;

  // workspace layout (floats): 16.4 MB total
  float* ws   = (float*)d_ws;
  float* h    = ws;                 // 512000
  float* hn   = ws + 512000;        // 512000
  float* abuf = ws + 1024000;       // 1024000 (reused as partials by final GEMM)
  float* bbuf = ws + 2048000;       // 1024000
  float* sbuf = ws + 3072000;       // 1024000
  float* part = abuf;               // KS_*32*6144 = 983040 floats

  patch_embed_k<<<dim3(125, 2), 256, 0, stream>>>(x, peW, peb, h);
  for (int l = 0; l < NL_; ++l) {
    ab_proj_k<<<dim3(125, 4), 256, 0, stream>>>(
        h, norm_w + l*D_, ipaW + l*INNER_*D_, ipbW + l*INNER_*D_, abuf, bbuf);
    conv_scan_k<<<dim3(B_, 2), 128, 0, stream>>>(
        abuf, bbuf, convW + l*INNER_*5, convb + l*INNER_,
        alpha + l*INNER_, beta + l*INNER_, gamma + l*INNER_, delta + l*INNER_, sbuf);
    out_proj_k<<<dim3(125, 2), 256, 0, stream>>>(sbuf, opW + l*D_*INNER_, h);
  }
  rmsnorm_final_k<<<dim3(1000), 256, 0, stream>>>(h, normf, hn);
  final_gemm_k<<<dim3(384, KS_), 512, 0, stream>>>(hn, outW, part);
  final_reduce_k<<<dim3(192), 256, 0, stream>>>(part, outb, out);
}